// Round 1
// baseline (363.130 us; speedup 1.0000x reference)
//
#include <hip/hip_runtime.h>
#include <math.h>

#define CC 256
#define NN 16384   // 128*128
#define NB 8

// ws layout (float offsets)
#define WV3_OFF   0                         // 256: v_w^T @ w3
#define WB3_OFF   256                       // 1:   w3 . v_b
#define S_OFF     257                       // 8:   softmax denominators
#define KL_OFF    272                       // NB*NN: k logits -> exp values
#define T3_OFF    (KL_OFF + NB*NN)          // NB*NN: wv3.x -> s values
#define HSUM_OFF  (T3_OFF + NB*NN)          // NB*128
#define HMK_OFF   (HSUM_OFF + NB*128)       // NB*128 (uint keys)
#define WSUM_OFF  (HMK_OFF + NB*128)        // NB*128
#define WMK_OFF   (WSUM_OFF + NB*128)       // NB*128 (uint keys)
#define XK_OFF    (WMK_OFF + NB*128)        // NB*CC
#define CF_OFF    (XK_OFF + NB*CC)          // NB*CC
#define WS_FLOATS (CF_OFF + NB*CC)

// monotone float<->uint mapping so unsigned atomicMax == float max
__device__ __forceinline__ unsigned fkey(float f){
  unsigned b = __float_as_uint(f);
  return (b & 0x80000000u) ? ~b : (b ^ 0x80000000u);
}
__device__ __forceinline__ float fdekey(unsigned k){
  unsigned b = (k & 0x80000000u) ? (k ^ 0x80000000u) : ~k;
  return __uint_as_float(b);
}
__device__ __forceinline__ float sigmoidf_(float z){ return 1.0f/(1.0f+expf(-z)); }

__device__ __forceinline__ float blockReduceSum(float v, volatile float* lds){
  #pragma unroll
  for (int m=1;m<=32;m<<=1) v += __shfl_xor(v, m, 64);
  int wid = threadIdx.x>>6;
  __syncthreads();
  if ((threadIdx.x&63)==0) lds[wid] = v;
  __syncthreads();
  return lds[0]+lds[1]+lds[2]+lds[3];
}
__device__ __forceinline__ float blockReduceMax(float v, volatile float* lds){
  #pragma unroll
  for (int m=1;m<=32;m<<=1) v = fmaxf(v, __shfl_xor(v, m, 64));
  int wid = threadIdx.x>>6;
  __syncthreads();
  if ((threadIdx.x&63)==0) lds[wid] = v;
  __syncthreads();
  return fmaxf(fmaxf(lds[0],lds[1]), fmaxf(lds[2],lds[3]));
}

// k0: wv3[c] = sum_o w3[o]*v_w[o,c];  wb3 = w3 . v_b
__global__ __launch_bounds__(256) void k0(const float* __restrict__ v_w,
                                          const float* __restrict__ v_b,
                                          const float* __restrict__ w3,
                                          float* __restrict__ ws){
  int t = threadIdx.x;
  float acc = 0.f;
  for (int o=0;o<CC;++o) acc += w3[o]*v_w[o*CC + t];
  ws[WV3_OFF + t] = acc;
  __shared__ float lds[4];
  float tot = blockReduceSum(w3[t]*v_b[t], lds);
  if (t==0) ws[WB3_OFF] = tot;
}

// k1: one pass over x. Accumulate kl (k_w.x), t3 (wv3.x), h/w pool stats.
// grid (16 n-tiles, 4 c-chunks, 8 batches), 256 threads.
__global__ __launch_bounds__(256) void k1(const float* __restrict__ x,
                                          const float* __restrict__ k_w,
                                          float* __restrict__ ws)
{
  const int t    = threadIdx.x;
  const int tile = blockIdx.x;   // n0 = tile*1024 -> rows tile*8 .. +7
  const int cc   = blockIdx.y;   // c0 = cc*64
  const int b    = blockIdx.z;
  const int n0   = tile*1024;
  const int c0   = cc*64;

  __shared__ float skw[64], swv[64];
  __shared__ float lws[4][128], lwm[4][128];
  __shared__ float lhs[8], lhm[8];
  if (t < 64){ skw[t] = k_w[c0+t]; swv[t] = ws[WV3_OFF + c0 + t]; }
  __syncthreads();

  float kla[4]={0,0,0,0}, t3a[4]={0,0,0,0}, cs[4]={0,0,0,0};
  float cm[4]={-INFINITY,-INFINITY,-INFINITY,-INFINITY};

  const float* xb = x + ((size_t)(b*CC + c0))*NN + n0 + t*4;
  #pragma unroll 4
  for (int c=0;c<64;++c){
    const float4 v = *(const float4*)(xb + (size_t)c*NN);
    const float kw = skw[c], wv = swv[c];
    kla[0] += kw*v.x; kla[1] += kw*v.y; kla[2] += kw*v.z; kla[3] += kw*v.w;
    t3a[0] += wv*v.x; t3a[1] += wv*v.y; t3a[2] += wv*v.z; t3a[3] += wv*v.w;
    cs[0] += v.x; cs[1] += v.y; cs[2] += v.z; cs[3] += v.w;
    cm[0] = fmaxf(cm[0], v.x); cm[1] = fmaxf(cm[1], v.y);
    cm[2] = fmaxf(cm[2], v.z); cm[3] = fmaxf(cm[3], v.w);
  }

  { // accumulate kl / t3 across the 4 c-chunks
    float* klp = ws + KL_OFF + (size_t)b*NN + n0 + t*4;
    float* t3p = ws + T3_OFF + (size_t)b*NN + n0 + t*4;
    atomicAdd(klp+0, kla[0]); atomicAdd(klp+1, kla[1]);
    atomicAdd(klp+2, kla[2]); atomicAdd(klp+3, kla[3]);
    atomicAdd(t3p+0, t3a[0]); atomicAdd(t3p+1, t3a[1]);
    atomicAdd(t3p+2, t3a[2]); atomicAdd(t3p+3, t3a[3]);
  }

  // --- h partials (row = tile*8 + (t>>5); fixed per thread) ---
  float hs = cs[0]+cs[1]+cs[2]+cs[3];
  float hm = fmaxf(fmaxf(cm[0],cm[1]), fmaxf(cm[2],cm[3]));
  #pragma unroll
  for (int m=1;m<=16;m<<=1){   // reduce over 32-lane half-wave (same row)
    hs += __shfl_xor(hs, m, 64);
    hm  = fmaxf(hm, __shfl_xor(hm, m, 64));
  }
  const int lane = t & 63, wid = t >> 6;
  if ((lane & 31) == 0){ lhs[t>>5] = hs; lhm[t>>5] = hm; }

  // --- w partials (w = (t*4)&127 + j); lane and lane^32 share w ---
  #pragma unroll
  for (int j=0;j<4;++j){
    cs[j] += __shfl_xor(cs[j], 32, 64);
    cm[j]  = fmaxf(cm[j], __shfl_xor(cm[j], 32, 64));
  }
  if (lane < 32){
    #pragma unroll
    for (int j=0;j<4;++j){ lws[wid][lane*4+j] = cs[j]; lwm[wid][lane*4+j] = cm[j]; }
  }
  __syncthreads();

  if (t < 128){
    float s = lws[0][t]+lws[1][t]+lws[2][t]+lws[3][t];
    float m = fmaxf(fmaxf(lwm[0][t],lwm[1][t]), fmaxf(lwm[2][t],lwm[3][t]));
    atomicAdd(ws + WSUM_OFF + b*128 + t, s);
    atomicMax((unsigned*)ws + WMK_OFF + b*128 + t, fkey(m));
  } else if (t < 136){
    int r = t - 128;
    atomicAdd(ws + HSUM_OFF + b*128 + tile*8 + r, lhs[r]);
    atomicMax((unsigned*)ws + HMK_OFF + b*128 + tile*8 + r, fkey(lhm[r]));
  }
}

// k2: per batch: softmax over kl (in-place -> exp values, store denom S),
// h_att/w_att from pool stats, then s = sigmoid((ha+wa)*(t3+wb3)+b3) in-place.
__global__ __launch_bounds__(256) void k2(float* __restrict__ ws,
                                          const float* __restrict__ w1, const float* __restrict__ b1,
                                          const float* __restrict__ w2, const float* __restrict__ b2,
                                          const float* __restrict__ b3)
{
  const int b = blockIdx.x, t = threadIdx.x;
  __shared__ float lds[4];
  __shared__ float ha[128], wa[128];
  float* kl = ws + KL_OFF + (size_t)b*NN;

  float m = -INFINITY;
  for (int j=t; j<NN; j+=256) m = fmaxf(m, kl[j]);
  m = blockReduceMax(m, lds);

  float s = 0.f;
  for (int j=t; j<NN; j+=256){ float e = expf(kl[j]-m); kl[j] = e; s += e; }
  s = blockReduceSum(s, lds);
  if (t==0) ws[S_OFF + b] = s;

  if (t < 128){
    float hsum = ws[HSUM_OFF + b*128 + t] * (1.0f/(256.0f*128.0f));
    float hmax = fdekey(((unsigned*)ws)[HMK_OFF + b*128 + t]);
    ha[t] = sigmoidf_(w1[0]*hmax + w1[1]*hsum + b1[0]);
  } else {
    int w = t - 128;
    float wsum = ws[WSUM_OFF + b*128 + w] * (1.0f/(256.0f*128.0f));
    float wmax = fdekey(((unsigned*)ws)[WMK_OFF + b*128 + w]);
    wa[w] = sigmoidf_(w2[0]*wmax + w2[1]*wsum + b2[0]);
  }
  __syncthreads();

  const float wb3 = ws[WB3_OFF], bb3 = b3[0];
  float* t3 = ws + T3_OFF + (size_t)b*NN;
  for (int j=t; j<NN; j+=256){
    float att = ha[j>>7] + wa[j&127];
    float tv  = t3[j] + wb3;
    t3[j] = sigmoidf_(att*tv + bb3);
  }
}

// k3: xk[b,c] = sum_n x[b,c,n] * e[b,n]   (unnormalized; /S later)
__global__ __launch_bounds__(256) void k3(const float* __restrict__ x,
                                          float* __restrict__ ws){
  const int c = blockIdx.x, b = blockIdx.y, t = threadIdx.x;
  const float4* x4 = (const float4*)(x + ((size_t)(b*CC + c))*NN);
  const float4* e4 = (const float4*)(ws + KL_OFF + (size_t)b*NN);
  float acc = 0.f;
  #pragma unroll 4
  for (int j=t; j<NN/4; j+=256){
    float4 xv = x4[j], ev = e4[j];
    acc += xv.x*ev.x + xv.y*ev.y + xv.z*ev.z + xv.w*ev.w;
  }
  __shared__ float lds[4];
  acc = blockReduceSum(acc, lds);
  if (t==0) ws[XK_OFF + b*CC + c] = acc;
}

// k4: channel_fea[b,o] = v_b[o] + sum_c v_w[o,c]*xk[b,c]/S[b]
__global__ __launch_bounds__(256) void k4(const float* __restrict__ v_w,
                                          const float* __restrict__ v_b,
                                          float* __restrict__ ws){
  const int b = blockIdx.x, t = threadIdx.x;
  __shared__ float xks[CC];
  const float Sinv = 1.0f / ws[S_OFF + b];
  xks[t] = ws[XK_OFF + b*CC + t] * Sinv;
  __syncthreads();
  float acc = v_b[t];
  for (int c=0;c<CC;++c) acc += v_w[t*CC + c]*xks[c];
  ws[CF_OFF + b*CC + t] = acc;
}

// k5: out = s[b,n]*cf[b,c] + x
__global__ __launch_bounds__(256) void k5(const float* __restrict__ x,
                                          const float* __restrict__ ws,
                                          float* __restrict__ out){
  const float4* x4 = (const float4*)x;
  float4* o4 = (float4*)out;
  const float4* s4 = (const float4*)(ws + T3_OFF);
  const float* cf = ws + CF_OFF;
  const int nq = NB*CC*NN/4;   // 8388608
  for (int q = blockIdx.x*256 + threadIdx.x; q < nq; q += gridDim.x*256){
    int bc = q >> 12;          // b*CC + c   (4096 float4 per (b,c))
    int b  = bc >> 8;
    int n4 = q & 4095;
    float f = cf[bc];
    float4 sv = s4[(size_t)b*4096 + n4];
    float4 xv = x4[q];
    float4 r;
    r.x = sv.x*f + xv.x; r.y = sv.y*f + xv.y;
    r.z = sv.z*f + xv.z; r.w = sv.w*f + xv.w;
    o4[q] = r;
  }
}

extern "C" void kernel_launch(void* const* d_in, const int* in_sizes, int n_in,
                              void* d_out, int out_size, void* d_ws, size_t ws_size,
                              hipStream_t stream) {
  const float* x   = (const float*)d_in[0];
  const float* v_w = (const float*)d_in[1];
  const float* v_b = (const float*)d_in[2];
  const float* k_w = (const float*)d_in[3];
  // d_in[4] = k_b: softmax is shift-invariant -> unused
  const float* w1  = (const float*)d_in[5];
  const float* b1  = (const float*)d_in[6];
  const float* w2  = (const float*)d_in[7];
  const float* b2  = (const float*)d_in[8];
  const float* w3  = (const float*)d_in[9];
  const float* b3  = (const float*)d_in[10];
  float* ws  = (float*)d_ws;
  float* out = (float*)d_out;

  hipMemsetAsync(d_ws, 0, (size_t)WS_FLOATS*sizeof(float), stream);
  k0<<<1, 256, 0, stream>>>(v_w, v_b, w3, ws);
  k1<<<dim3(16,4,NB), 256, 0, stream>>>(x, k_w, ws);
  k2<<<NB, 256, 0, stream>>>(ws, w1, b1, w2, b2, b3);
  k3<<<dim3(CC,NB), 256, 0, stream>>>(x, ws);
  k4<<<NB, 256, 0, stream>>>(v_w, v_b, ws);
  k5<<<2048, 256, 0, stream>>>(x, ws, out);
}

// Round 3
// 325.204 us; speedup vs baseline: 1.1166x; 1.1166x over previous
//
#include <hip/hip_runtime.h>
#include <math.h>

#define CC   256
#define NN   16384   // 128*128
#define NB   8
#define TILE 512     // spatial positions per k1 block (4 rows of 128)
#define NT   32      // NN / TILE

// ws layout (float offsets)
#define WV3_OFF   0                    // 256: v_w^T @ w3           [zeroed]
#define WB3_OFF   256                  // 1:   w3 . v_b
#define S_OFF     264                  // 8:   softmax denominators [zeroed]
#define HSUM_OFF  272                  // NB*128 (plain stores)
#define HMAX_OFF  1296                 // NB*128 (plain stores)
#define WSUM_OFF  2320                 // NB*128 [zeroed]
#define WMK_OFF   3344                 // NB*128 uint keys [zeroed]
#define XK_OFF    4368                 // NB*CC [zeroed]
#define CF_OFF    6416                 // NB*CC
#define HA_OFF    8464                 // NB*128
#define WA_OFF    9488                 // NB*128
#define T3_OFF    10512                // NB*NN
#define ZERO_BYTES (6416*4)            // zero WV3..XK in one memset

__device__ __forceinline__ unsigned fkey(float f){
  unsigned b = __float_as_uint(f);
  return (b & 0x80000000u) ? ~b : (b ^ 0x80000000u);
}
__device__ __forceinline__ float fdekey(unsigned k){
  unsigned b = (k & 0x80000000u) ? (k ^ 0x80000000u) : ~k;
  return __uint_as_float(b);
}
__device__ __forceinline__ float sigmoidf_(float z){ return 1.0f/(1.0f+expf(-z)); }

// k0: wv3[c] = sum_o w3[o]*v_w[o,c] (16-way o-split, atomicAdd); wb3 = w3.v_b
__global__ __launch_bounds__(256) void k0(const float* __restrict__ v_w,
                                          const float* __restrict__ v_b,
                                          const float* __restrict__ w3,
                                          float* __restrict__ ws){
  const int t = threadIdx.x, g = blockIdx.x;
  float acc = 0.f;
  #pragma unroll
  for (int i=0;i<16;++i){
    int o = g*16 + i;
    acc += w3[o]*v_w[o*CC + t];
  }
  atomicAdd(ws + WV3_OFF + t, acc);
  if (g == 0){
    float v = w3[t]*v_b[t];
    #pragma unroll
    for (int m=1;m<=32;m<<=1) v += __shfl_xor(v, m, 64);
    __shared__ float l[4];
    if ((t&63)==0) l[t>>6] = v;
    __syncthreads();
    if (t==0) ws[WB3_OFF] = l[0]+l[1]+l[2]+l[3];
  }
}

// k1: the big fused pass. Block = (tile of 512 positions, batch); covers all 256 c.
// Phase 1: stream x (HBM): kl, t3, pool stats.  e=exp(kl) stays in registers.
// Phase 2: re-read tile (L2/L3): xk[c] partials via wave butterflies.
__global__ __launch_bounds__(256) void k1(const float* __restrict__ x,
                                          const float* __restrict__ k_w,
                                          float* __restrict__ ws)
{
  const int t = threadIdx.x, lane = t&63, wv = t>>6;
  const int tile = blockIdx.x, b = blockIdx.y;
  const int n0 = tile*TILE;

  __shared__ float skw[CC], swv[CC];
  __shared__ float lred[4][128];
  __shared__ float sS[4];
  skw[t] = k_w[t];
  swv[t] = ws[WV3_OFF + t];
  __syncthreads();

  const float* xb = x + (size_t)b*CC*NN + n0 + 2*t;

  float kl0=0.f,kl1=0.f,t30=0.f,t31=0.f,cs0=0.f,cs1=0.f;
  float cm0=-INFINITY, cm1=-INFINITY;
  #pragma unroll 8
  for (int c=0;c<CC;++c){
    const float2 v = *(const float2*)(xb + (size_t)c*NN);
    const float kw = skw[c], wvv = swv[c];
    kl0 += kw*v.x;  kl1 += kw*v.y;
    t30 += wvv*v.x; t31 += wvv*v.y;
    cs0 += v.x;     cs1 += v.y;
    cm0 = fmaxf(cm0, v.x); cm1 = fmaxf(cm1, v.y);
  }

  // t3 raw store
  *(float2*)(ws + T3_OFF + (size_t)b*NN + n0 + 2*t) = make_float2(t30, t31);

  // h stats: wave wv owns global row tile*4+wv exclusively -> plain store
  float hs = cs0+cs1, hm = fmaxf(cm0, cm1);
  #pragma unroll
  for (int m=1;m<=32;m<<=1){
    hs += __shfl_xor(hs, m, 64);
    hm  = fmaxf(hm, __shfl_xor(hm, m, 64));
  }
  if (lane == 0){
    ws[HSUM_OFF + b*128 + tile*4 + wv] = hs;
    ws[HMAX_OFF + b*128 + tile*4 + wv] = hm;
  }

  // w stats: position w = 2*lane(+1), same mapping in all 4 waves
  lred[wv][2*lane] = cs0; lred[wv][2*lane+1] = cs1;
  __syncthreads();
  if (t < 128)
    atomicAdd(ws + WSUM_OFF + b*128 + t, lred[0][t]+lred[1][t]+lred[2][t]+lred[3][t]);
  __syncthreads();
  lred[wv][2*lane] = cm0; lred[wv][2*lane+1] = cm1;
  __syncthreads();
  if (t < 128){
    float m_ = fmaxf(fmaxf(lred[0][t],lred[1][t]), fmaxf(lred[2][t],lred[3][t]));
    atomicMax((unsigned*)ws + WMK_OFF + b*128 + t, fkey(m_));
  }

  // softmax numerators (registers only) + denominator partial
  const float e0 = expf(kl0), e1 = expf(kl1);
  float es = e0 + e1;
  #pragma unroll
  for (int m=1;m<=32;m<<=1) es += __shfl_xor(es, m, 64);
  if (lane == 0) sS[wv] = es;
  __syncthreads();
  if (t == 0) atomicAdd(ws + S_OFF + b, sS[0]+sS[1]+sS[2]+sS[3]);

  // Phase 2: xk[c] partial = sum over this tile of x[c,p]*e[p]  (re-read from L2/L3)
  float xkacc0=0.f, xkacc1=0.f, xkacc2=0.f, xkacc3=0.f;
  #pragma unroll
  for (int cg=0; cg<4; ++cg){
    #pragma unroll 8
    for (int cl=0; cl<64; ++cl){
      const int c = cg*64 + cl;
      const float2 v = *(const float2*)(xb + (size_t)c*NN);
      float p = v.x*e0 + v.y*e1;
      #pragma unroll
      for (int m=1;m<=32;m<<=1) p += __shfl_xor(p, m, 64);
      if (lane == cl){
        if      (cg==0) xkacc0 = p;
        else if (cg==1) xkacc1 = p;
        else if (cg==2) xkacc2 = p;
        else            xkacc3 = p;
      }
    }
  }
  atomicAdd(ws + XK_OFF + b*CC +   0 + lane, xkacc0);
  atomicAdd(ws + XK_OFF + b*CC +  64 + lane, xkacc1);
  atomicAdd(ws + XK_OFF + b*CC + 128 + lane, xkacc2);
  atomicAdd(ws + XK_OFF + b*CC + 192 + lane, xkacc3);
}

// k4: per batch: ha/wa from pool stats; cf = v_b + v_w @ (xk/S)
__global__ __launch_bounds__(256) void k4(const float* __restrict__ v_w,
                                          const float* __restrict__ v_b,
                                          const float* __restrict__ w1, const float* __restrict__ b1,
                                          const float* __restrict__ w2, const float* __restrict__ b2,
                                          float* __restrict__ ws){
  const int b = blockIdx.x, t = threadIdx.x;
  const float inv = 1.0f/(256.0f*128.0f);
  if (t < 128){
    float hsum = ws[HSUM_OFF + b*128 + t] * inv;
    float hmax = ws[HMAX_OFF + b*128 + t];
    ws[HA_OFF + b*128 + t] = sigmoidf_(w1[0]*hmax + w1[1]*hsum + b1[0]);
  } else {
    int w = t - 128;
    float wsum = ws[WSUM_OFF + b*128 + w] * inv;
    float wmax = fdekey(((unsigned*)ws)[WMK_OFF + b*128 + w]);
    ws[WA_OFF + b*128 + w] = sigmoidf_(w2[0]*wmax + w2[1]*wsum + b2[0]);
  }
  __shared__ float xks[CC];
  const float Sinv = 1.0f / ws[S_OFF + b];
  xks[t] = ws[XK_OFF + b*CC + t] * Sinv;
  __syncthreads();
  float acc = v_b[t];
  #pragma unroll 8
  for (int c=0;c<CC;++c) acc += v_w[t*CC + c]*xks[c];
  ws[CF_OFF + b*CC + t] = acc;
}

// k5: out = sigmoid((ha+wa)*(t3+wb3)+b3) * cf[b,c] + x
__global__ __launch_bounds__(256) void k5(const float* __restrict__ x,
                                          const float* __restrict__ ws,
                                          const float* __restrict__ b3,
                                          float* __restrict__ out){
  const float4* x4 = (const float4*)x;
  float4* o4 = (float4*)out;
  const float4* t34 = (const float4*)(ws + T3_OFF);
  const float4* wa4 = (const float4*)(ws + WA_OFF);
  const float* ha = ws + HA_OFF;
  const float* cf = ws + CF_OFF;
  const float wb3 = ws[WB3_OFF];
  const float bb3 = b3[0];
  const int nq = NB*CC*NN/4;   // 8388608
  for (int q = blockIdx.x*256 + threadIdx.x; q < nq; q += gridDim.x*256){
    const int bc = q >> 12;          // b*CC + c
    const int b  = bc >> 8;
    const int n4 = q & 4095;         // float4 index within the image
    const float f = cf[bc];
    const float hav = ha[b*128 + (n4>>5)];
    const float4 wav = wa4[b*32 + (n4&31)];
    const float4 tv = t34[(size_t)b*4096 + n4];
    const float4 xv = x4[q];
    float4 r;
    r.x = sigmoidf_((hav+wav.x)*(tv.x+wb3)+bb3)*f + xv.x;
    r.y = sigmoidf_((hav+wav.y)*(tv.y+wb3)+bb3)*f + xv.y;
    r.z = sigmoidf_((hav+wav.z)*(tv.z+wb3)+bb3)*f + xv.z;
    r.w = sigmoidf_((hav+wav.w)*(tv.w+wb3)+bb3)*f + xv.w;
    o4[q] = r;
  }
}

extern "C" void kernel_launch(void* const* d_in, const int* in_sizes, int n_in,
                              void* d_out, int out_size, void* d_ws, size_t ws_size,
                              hipStream_t stream) {
  const float* x   = (const float*)d_in[0];
  const float* v_w = (const float*)d_in[1];
  const float* v_b = (const float*)d_in[2];
  const float* k_w = (const float*)d_in[3];
  // d_in[4] = k_b: softmax shift-invariant -> unused
  const float* w1  = (const float*)d_in[5];
  const float* b1  = (const float*)d_in[6];
  const float* w2  = (const float*)d_in[7];
  const float* b2  = (const float*)d_in[8];
  const float* w3  = (const float*)d_in[9];
  const float* b3  = (const float*)d_in[10];
  float* ws  = (float*)d_ws;
  float* out = (float*)d_out;

  hipMemsetAsync(d_ws, 0, ZERO_BYTES, stream);
  k0<<<16, 256, 0, stream>>>(v_w, v_b, w3, ws);
  k1<<<dim3(NT, NB), 256, 0, stream>>>(x, k_w, ws);
  k4<<<NB, 256, 0, stream>>>(v_w, v_b, w1, b1, w2, b2, ws);
  k5<<<2048, 256, 0, stream>>>(x, ws, b3, out);
}

// Round 5
// 307.449 us; speedup vs baseline: 1.1811x; 1.0578x over previous
//
#include <hip/hip_runtime.h>
#include <math.h>

#define CC   256
#define NN   16384   // 128*128
#define NB   8
#define TILE 512     // spatial positions per k1a block (4 rows of 128)
#define NT   32      // NN/TILE
#define NCH  4       // channel chunks
#define CHC  64      // channels per chunk

// ws layout (float offsets) — keep ws small (~1.1 MB proven-safe territory)
#define WV3_OFF   0                          // 256 [zeroed]
#define WB3_OFF   256                        // 1
#define S_OFF     264                        // 8  [zeroed]
#define HSUM_OFF  272                        // NB*128 [zeroed]
#define HMK_OFF   1296                       // NB*128 uint keys [zeroed]
#define WSUM_OFF  2320                       // NB*128 [zeroed]
#define WMK_OFF   3344                       // NB*128 uint keys [zeroed]
#define ZERO_END  4368                       // zero [0, ZERO_END) floats
#define HA_OFF    4368                       // NB*128
#define WA_OFF    5392                       // NB*128
#define CF_OFF    6416                       // NB*CC
#define XK_OFF    8464                       // NB*CC
#define EK_OFF    16384                      // NB*NN  (e = exp(kl))
#define T3C_OFF   (EK_OFF + NB*NN)           // NB*NN  (t3 combined + wb3)
// d_out scratch (float offsets into out buffer; consumed by k1b before k5 writes)
#define OKLP_OFF  0                          // NCH*NB*NN kl partials
#define OT3P_OFF  (NCH*NB*NN)                // NCH*NB*NN t3 partials

__device__ __forceinline__ unsigned fkey(float f){
  unsigned b = __float_as_uint(f);
  return (b & 0x80000000u) ? ~b : (b ^ 0x80000000u);
}
__device__ __forceinline__ float fdekey(unsigned k){
  unsigned b = (k & 0x80000000u) ? (k ^ 0x80000000u) : ~k;
  return __uint_as_float(b);
}
__device__ __forceinline__ float sigmoidf_(float z){ return 1.0f/(1.0f+expf(-z)); }

// k0: wv3[c] = sum_o w3[o]*v_w[o,c] (64 blocks x 4 o's, atomicAdd); wb3 = w3.v_b
__global__ __launch_bounds__(256) void k0(const float* __restrict__ v_w,
                                          const float* __restrict__ v_b,
                                          const float* __restrict__ w3,
                                          float* __restrict__ ws){
  const int t = threadIdx.x, g = blockIdx.x;
  float acc = 0.f;
  #pragma unroll
  for (int i=0;i<4;++i){
    int o = g*4 + i;
    acc += w3[o]*v_w[o*CC + t];
  }
  atomicAdd(ws + WV3_OFF + t, acc);
  if (g == 0){
    float v = w3[t]*v_b[t];
    #pragma unroll
    for (int m=1;m<=32;m<<=1) v += __shfl_xor(v, m, 64);
    __shared__ float l[4];
    if ((t&63)==0) l[t>>6] = v;
    __syncthreads();
    if (t==0) ws[WB3_OFF] = l[0]+l[1]+l[2]+l[3];
  }
}

// k1a: pure streaming pass. Block = (tile of 512 pos, channel-chunk of 64, batch).
// Stores kl/t3 partials into d_out scratch (atomic-free), pool stats via ws atomics.
__global__ __launch_bounds__(256) void k1a(const float* __restrict__ x,
                                           const float* __restrict__ k_w,
                                           float* __restrict__ ws,
                                           float* __restrict__ oscratch)
{
  const int t = threadIdx.x, lane = t&63, wv = t>>6;
  const int tile = blockIdx.x;          // 0..31
  const int q    = blockIdx.y;          // 0..3
  const int b    = blockIdx.z;
  const int n0   = tile*TILE;
  const int c0   = q*CHC;

  __shared__ float skw[CHC], swv[CHC];
  __shared__ float lred[4][128];
  if (t < CHC){ skw[t] = k_w[c0+t]; swv[t] = ws[WV3_OFF + c0 + t]; }
  __syncthreads();

  const float* xb = x + ((size_t)(b*CC + c0))*NN + n0 + 2*t;

  float kl0=0.f,kl1=0.f,t30=0.f,t31=0.f,cs0=0.f,cs1=0.f;
  float cm0=-INFINITY, cm1=-INFINITY;
  #pragma unroll 8
  for (int c=0;c<CHC;++c){
    const float2 v = *(const float2*)(xb + (size_t)c*NN);
    const float kw = skw[c], wvv = swv[c];
    kl0 += kw*v.x;  kl1 += kw*v.y;
    t30 += wvv*v.x; t31 += wvv*v.y;
    cs0 += v.x;     cs1 += v.y;
    cm0 = fmaxf(cm0, v.x); cm1 = fmaxf(cm1, v.y);
  }

  const size_t pidx = ((size_t)(q*NB + b))*NN + n0 + 2*t;
  *(float2*)(oscratch + OKLP_OFF + pidx) = make_float2(kl0, kl1);
  *(float2*)(oscratch + OT3P_OFF + pidx) = make_float2(t30, t31);

  // h stats: wave wv owns row tile*4+wv (partial over this c-chunk)
  float hs = cs0+cs1, hm = fmaxf(cm0, cm1);
  #pragma unroll
  for (int m=1;m<=32;m<<=1){
    hs += __shfl_xor(hs, m, 64);
    hm  = fmaxf(hm, __shfl_xor(hm, m, 64));
  }
  if (lane == 0){
    atomicAdd(ws + HSUM_OFF + b*128 + tile*4 + wv, hs);
    atomicMax((unsigned*)ws + HMK_OFF + b*128 + tile*4 + wv, fkey(hm));
  }

  // w stats: position w = 2*(t&63)(+1) within row; same mapping in all 4 waves
  lred[wv][2*lane] = cs0; lred[wv][2*lane+1] = cs1;
  __syncthreads();
  if (t < 128)
    atomicAdd(ws + WSUM_OFF + b*128 + t, lred[0][t]+lred[1][t]+lred[2][t]+lred[3][t]);
  __syncthreads();
  lred[wv][2*lane] = cm0; lred[wv][2*lane+1] = cm1;
  __syncthreads();
  if (t < 128){
    float m_ = fmaxf(fmaxf(lred[0][t],lred[1][t]), fmaxf(lred[2][t],lred[3][t]));
    atomicMax((unsigned*)ws + WMK_OFF + b*128 + t, fkey(m_));
  }
}

// k1b: combine partials: e = exp(sum kl), t3c = sum t3 + wb3, S partial
__global__ __launch_bounds__(256) void k1b(float* __restrict__ ws,
                                           const float* __restrict__ oscratch){
  const int chunk = blockIdx.x;   // 0..31 (512 positions each)
  const int b = blockIdx.y;
  const int t = threadIdx.x, lane = t&63, wv = t>>6;
  const int n = chunk*512 + 2*t;
  const float wb3 = ws[WB3_OFF];

  float kl0=0.f,kl1=0.f,t30=0.f,t31=0.f;
  #pragma unroll
  for (int qq=0; qq<NCH; ++qq){
    const size_t pidx = ((size_t)(qq*NB + b))*NN + n;
    const float2 kv = *(const float2*)(oscratch + OKLP_OFF + pidx);
    const float2 tv = *(const float2*)(oscratch + OT3P_OFF + pidx);
    kl0 += kv.x; kl1 += kv.y; t30 += tv.x; t31 += tv.y;
  }
  const float e0 = expf(kl0), e1 = expf(kl1);
  *(float2*)(ws + EK_OFF  + (size_t)b*NN + n) = make_float2(e0, e1);
  *(float2*)(ws + T3C_OFF + (size_t)b*NN + n) = make_float2(t30+wb3, t31+wb3);

  float es = e0 + e1;
  #pragma unroll
  for (int m=1;m<=32;m<<=1) es += __shfl_xor(es, m, 64);
  __shared__ float sS[4];
  if (lane == 0) sS[wv] = es;
  __syncthreads();
  if (t == 0) atomicAdd(ws + S_OFF + b, sS[0]+sS[1]+sS[2]+sS[3]);
}

// k3: xk[b,c] = sum_n x[b,c,n]*e[b,n]  (one block per (c,b), atomic-free)
__global__ __launch_bounds__(256) void k3(const float* __restrict__ x,
                                          float* __restrict__ ws){
  const int c = blockIdx.x, b = blockIdx.y, t = threadIdx.x;
  const float4* x4 = (const float4*)(x + ((size_t)(b*CC + c))*NN);
  const float4* e4 = (const float4*)(ws + EK_OFF + (size_t)b*NN);
  float acc = 0.f;
  #pragma unroll 4
  for (int j=t; j<NN/4; j+=256){
    const float4 xv = x4[j], ev = e4[j];
    acc += xv.x*ev.x + xv.y*ev.y + xv.z*ev.z + xv.w*ev.w;
  }
  #pragma unroll
  for (int m=1;m<=32;m<<=1) acc += __shfl_xor(acc, m, 64);
  __shared__ float l[4];
  if ((t&63)==0) l[t>>6] = acc;
  __syncthreads();
  if (t==0) ws[XK_OFF + b*CC + c] = l[0]+l[1]+l[2]+l[3];
}

// k4: block (oc,b). oc==0 also computes ha/wa. GEMV cf = v_b + v_w @ (xk/S),
// coalesced: 4 lanes per output row o, each reads float4 runs of v_w[o,:].
__global__ __launch_bounds__(256) void k4(const float* __restrict__ v_w,
                                          const float* __restrict__ v_b,
                                          const float* __restrict__ w1, const float* __restrict__ b1,
                                          const float* __restrict__ w2, const float* __restrict__ b2,
                                          float* __restrict__ ws){
  const int oc = blockIdx.x, b = blockIdx.y, t = threadIdx.x;
  if (oc == 0){
    const float inv = 1.0f/(256.0f*128.0f);
    if (t < 128){
      float hsum = ws[HSUM_OFF + b*128 + t] * inv;
      float hmax = fdekey(((unsigned*)ws)[HMK_OFF + b*128 + t]);
      ws[HA_OFF + b*128 + t] = sigmoidf_(w1[0]*hmax + w1[1]*hsum + b1[0]);
    } else {
      int w = t - 128;
      float wsum = ws[WSUM_OFF + b*128 + w] * inv;
      float wmax = fdekey(((unsigned*)ws)[WMK_OFF + b*128 + w]);
      ws[WA_OFF + b*128 + w] = sigmoidf_(w2[0]*wmax + w2[1]*wsum + b2[0]);
    }
  }
  __shared__ float xks[CC];
  const float Sinv = 1.0f / ws[S_OFF + b];
  xks[t] = ws[XK_OFF + b*CC + t] * Sinv;
  __syncthreads();
  const float4* xk4 = (const float4*)xks;

  const int o  = oc*64 + (t>>2);     // output row
  const int qq = t & 3;
  const float4* vw4 = (const float4*)(v_w + (size_t)o*CC);
  float acc = 0.f;
  #pragma unroll
  for (int i=0;i<16;++i){
    const int c4 = qq + 4*i;
    const float4 wv = vw4[c4];
    const float4 xv = xk4[c4];
    acc += wv.x*xv.x + wv.y*xv.y + wv.z*xv.z + wv.w*xv.w;
  }
  acc += __shfl_xor(acc, 1, 64);
  acc += __shfl_xor(acc, 2, 64);
  if (qq == 0) ws[CF_OFF + b*CC + o] = acc + v_b[o];
}

// k5: out = sigmoid((ha+wa)*t3c + b3) * cf[b,c] + x
__global__ __launch_bounds__(256) void k5(const float* __restrict__ x,
                                          const float* __restrict__ ws,
                                          const float* __restrict__ b3,
                                          float* __restrict__ out){
  const float4* x4 = (const float4*)x;
  float4* o4 = (float4*)out;
  const float4* t34 = (const float4*)(ws + T3C_OFF);
  const float4* wa4 = (const float4*)(ws + WA_OFF);
  const float* ha = ws + HA_OFF;
  const float* cf = ws + CF_OFF;
  const float bb3 = b3[0];
  const int nq = NB*CC*NN/4;   // 8388608
  for (int q = blockIdx.x*256 + threadIdx.x; q < nq; q += gridDim.x*256){
    const int bc = q >> 12;          // b*CC + c
    const int b  = bc >> 8;
    const int n4 = q & 4095;
    const float f = cf[bc];
    const float hav = ha[b*128 + (n4>>5)];
    const float4 wav = wa4[b*32 + (n4&31)];
    const float4 tv = t34[(size_t)b*4096 + n4];
    const float4 xv = x4[q];
    float4 r;
    r.x = sigmoidf_((hav+wav.x)*tv.x + bb3)*f + xv.x;
    r.y = sigmoidf_((hav+wav.y)*tv.y + bb3)*f + xv.y;
    r.z = sigmoidf_((hav+wav.z)*tv.z + bb3)*f + xv.z;
    r.w = sigmoidf_((hav+wav.w)*tv.w + bb3)*f + xv.w;
    o4[q] = r;
  }
}

extern "C" void kernel_launch(void* const* d_in, const int* in_sizes, int n_in,
                              void* d_out, int out_size, void* d_ws, size_t ws_size,
                              hipStream_t stream) {
  const float* x   = (const float*)d_in[0];
  const float* v_w = (const float*)d_in[1];
  const float* v_b = (const float*)d_in[2];
  const float* k_w = (const float*)d_in[3];
  // d_in[4] = k_b: softmax shift-invariant -> unused
  const float* w1  = (const float*)d_in[5];
  const float* b1  = (const float*)d_in[6];
  const float* w2  = (const float*)d_in[7];
  const float* b2  = (const float*)d_in[8];
  const float* w3  = (const float*)d_in[9];
  const float* b3  = (const float*)d_in[10];
  float* ws  = (float*)d_ws;
  float* out = (float*)d_out;

  hipMemsetAsync(d_ws, 0, (size_t)ZERO_END*sizeof(float), stream);
  k0 <<<64, 256, 0, stream>>>(v_w, v_b, w3, ws);
  k1a<<<dim3(NT, NCH, NB), 256, 0, stream>>>(x, k_w, ws, out);
  k1b<<<dim3(32, NB), 256, 0, stream>>>(ws, out);
  k3 <<<dim3(CC, NB), 256, 0, stream>>>(x, ws);
  k4 <<<dim3(4, NB), 256, 0, stream>>>(v_w, v_b, w1, b1, w2, b2, ws);
  k5 <<<2048, 256, 0, stream>>>(x, ws, b3, out);
}